// Round 7
// baseline (228.662 us; speedup 1.0000x reference)
//
#include <hip/hip_runtime.h>
#include <hip/hip_fp16.h>

// GCN 2-layer forward: CSR-gather + fp16-MFMA GEMMs (fp32 accumulate).
// N=50000, E=800000, IN=128, HID=128, OUT=64.
// R7: 16-deep gather bursts w/ float4 pair loads (real MLP); fill+gemm128 grid-fused.

typedef _Float16 f16;
typedef __attribute__((ext_vector_type(8))) _Float16 f16x8;
typedef __attribute__((ext_vector_type(4))) float f32x4;

// Pass 1: deg histogram + per-edge within-row position; first blocks also
// transpose W1/W2 to fp16 k-contiguous (stride 136).
__global__ __launch_bounds__(256) void deg_prep_kernel(const int* __restrict__ dst,
                                                       int* __restrict__ deg,
                                                       int* __restrict__ posw,
                                                       const float* __restrict__ W1,
                                                       const float* __restrict__ W2,
                                                       f16* __restrict__ Wt1,
                                                       f16* __restrict__ Wt2, int E) {
    int gid = blockIdx.x * 256 + threadIdx.x;
    if (gid < E) posw[gid] = atomicAdd(&deg[dst[gid]], 1);
    if (gid < 128 * 128) {
        int k = gid >> 7, c = gid & 127;
        Wt1[c * 136 + k] = (f16)W1[gid];
    } else if (gid < 128 * 128 + 128 * 64) {
        int j = gid - 128 * 128;
        int k = j >> 6, c = j & 63;
        Wt2[c * 136 + k] = (f16)W2[j];
    }
}

// Per-block exclusive scan (block=1024); block sums to bsum; dinv on the side.
__global__ __launch_bounds__(1024) void scan1_kernel(const int* __restrict__ deg,
                                                     int* __restrict__ rowptr,
                                                     int* __restrict__ bsum,
                                                     float* __restrict__ dinv, int N) {
    __shared__ int wsum[16];
    const int tid = threadIdx.x, lane = tid & 63, wid = tid >> 6;
    const int idx = blockIdx.x * 1024 + tid;
    int v = (idx < N) ? deg[idx] : 0;
    if (idx < N) dinv[idx] = rsqrtf((float)v + 1.0f);
    int incl = v;
#pragma unroll
    for (int off = 1; off < 64; off <<= 1) {
        int t = __shfl_up(incl, off, 64);
        if (lane >= off) incl += t;
    }
    if (lane == 63) wsum[wid] = incl;
    __syncthreads();
    if (wid == 0) {
        int s = (lane < 16) ? wsum[lane] : 0;
#pragma unroll
        for (int off = 1; off < 16; off <<= 1) {
            int t = __shfl_up(s, off, 64);
            if (lane >= off) s += t;
        }
        if (lane < 16) wsum[lane] = s;
    }
    __syncthreads();
    int waveoff = (wid == 0) ? 0 : wsum[wid - 1];
    if (idx < N) rowptr[idx] = waveoff + incl - v;
    if (tid == 1023) bsum[blockIdx.x] = waveoff + incl;
}

// Merged scan2+scan3: each block wave-reduces its exclusive prefix of bsum
// (nb <= 64) and adds it; block 0 also writes rowptr[N] = total.
__global__ __launch_bounds__(1024) void scan23_kernel(int* __restrict__ rowptr,
                                                      const int* __restrict__ bsum,
                                                      int N, int nb) {
    __shared__ int pfx_s;
    const int tid = threadIdx.x;
    if (tid < 64) {
        int v = (tid < nb && tid < blockIdx.x) ? bsum[tid] : 0;
#pragma unroll
        for (int off = 32; off; off >>= 1) v += __shfl_xor(v, off, 64);
        if (tid == 0) pfx_s = v;
    }
    if (blockIdx.x == 0 && tid >= 64 && tid < 128) {
        int l = tid - 64;
        int v = (l < nb) ? bsum[l] : 0;
#pragma unroll
        for (int off = 32; off; off >>= 1) v += __shfl_xor(v, off, 64);
        if (l == 0) rowptr[N] = v;
    }
    __syncthreads();
    int idx = blockIdx.x * 1024 + tid;
    if (idx < N) rowptr[idx] += pfx_s;
}

// GEMM body: H[N][KOUT](fp16) = X[N][128] @ Wt via mfma_f32_16x16x32_f16.
// 256 thr = 4 waves x 16 rows; Wl is KOUT*136 halves of LDS.
template <int KOUT, bool F32IN>
__device__ __forceinline__ void gemm_body(int bid, const void* __restrict__ Xv,
                                          const f16* __restrict__ Wt,
                                          f16* __restrict__ H, int N, f16* Wl) {
    constexpr int CT = KOUT / 16;
    const int tid = threadIdx.x;
    constexpr int CHUNKS = KOUT * 136 / 8;
    {
        const uint4* s = (const uint4*)Wt;
        uint4* d = (uint4*)Wl;
        for (int i = tid; i < CHUNKS; i += 256) d[i] = s[i];
    }
    __syncthreads();

    const int lane = tid & 63, wid = tid >> 6;
    const int c = lane & 15, kseg = lane >> 4;
    const int row0 = bid * 64 + wid * 16;
    int arow = row0 + c;
    if (arow >= N) arow = N - 1;

    f32x4 acc[CT];
#pragma unroll
    for (int t = 0; t < CT; ++t) acc[t] = (f32x4){0.f, 0.f, 0.f, 0.f};

#pragma unroll
    for (int kt = 0; kt < 4; ++kt) {
        const int k0 = kt * 32;
        f16x8 a;
        if (F32IN) {
            const float* xp = (const float*)Xv + (long)arow * 128 + k0 + kseg * 8;
            float4 x0 = *(const float4*)xp;
            float4 x1 = *(const float4*)(xp + 4);
            a[0] = (f16)x0.x; a[1] = (f16)x0.y; a[2] = (f16)x0.z; a[3] = (f16)x0.w;
            a[4] = (f16)x1.x; a[5] = (f16)x1.y; a[6] = (f16)x1.z; a[7] = (f16)x1.w;
        } else {
            a = *(const f16x8*)((const f16*)Xv + (long)arow * 128 + k0 + kseg * 8);
        }
#pragma unroll
        for (int ct = 0; ct < CT; ++ct) {
            f16x8 b = *(const f16x8*)&Wl[(ct * 16 + c) * 136 + k0 + kseg * 8];
            acc[ct] = __builtin_amdgcn_mfma_f32_16x16x32_f16(a, b, acc[ct], 0, 0, 0);
        }
    }

    const int rbase = row0 + kseg * 4;
#pragma unroll
    for (int ct = 0; ct < CT; ++ct)
#pragma unroll
        for (int r = 0; r < 4; ++r) {
            int row = rbase + r;
            if (row < N) H[(long)row * KOUT + ct * 16 + c] = (f16)acc[ct][r];
        }
}

// Standalone gemm (layer 2).
template <int KOUT, bool F32IN>
__global__ __launch_bounds__(256) void gemm_kernel(const void* __restrict__ Xv,
                                                   const f16* __restrict__ Wt,
                                                   f16* __restrict__ H, int N) {
    __shared__ f16 Wl[KOUT * 136];
    gemm_body<KOUT, F32IN>(blockIdx.x, Xv, Wt, H, N, Wl);
}

// Fused: blocks [0,GB) run gemm128 on x->h1; blocks [GB,GB+FB) run CSR fill.
__global__ __launch_bounds__(256) void fill_gemm_kernel(const int* __restrict__ src,
                                                        const int* __restrict__ dst,
                                                        const int* __restrict__ posw,
                                                        const float* __restrict__ dinv,
                                                        const int* __restrict__ rowptr,
                                                        float2* __restrict__ pairs, int E,
                                                        const float* __restrict__ x,
                                                        const f16* __restrict__ Wt1,
                                                        f16* __restrict__ h1, int N, int GB) {
    __shared__ f16 Wl[128 * 136];
    if ((int)blockIdx.x < GB) {
        gemm_body<128, true>(blockIdx.x, x, Wt1, h1, N, Wl);
        return;
    }
    int e = (blockIdx.x - GB) * 256 + threadIdx.x;
    if (e >= E) return;
    int s = src[e], d = dst[e];
    float2 p;
    p.x = __int_as_float(s);
    p.y = dinv[s] * dinv[d];
    pairs[rowptr[d] + posw[e]] = p;
}

// One wave per node; fp16 payloads, fp32 accumulate.
// Pairs loaded as float4 (2 edges/load); bursts of 16/4/1 for deep MLP.
template <int F, bool RELU, bool OUTF16>
__global__ __launch_bounds__(256) void gather_kernel(const void* __restrict__ Hv,
                                                     const int* __restrict__ rowptr,
                                                     const float2* __restrict__ pairs,
                                                     const float* __restrict__ dinv,
                                                     const float* __restrict__ bias,
                                                     void* __restrict__ outv, int N) {
    const int wid = threadIdx.x >> 6;
    const int lane = threadIdx.x & 63;
    const int node = blockIdx.x * 4 + wid;
    if (node >= N) return;
    const int start = rowptr[node], end = rowptr[node + 1];
    const float4* pp4 = (const float4*)pairs;  // 2 edges per float4; ws base 16B-aligned

    if (F == 128) {
        const __half2* Hu = (const __half2*)Hv;
        float ax = 0.f, ay = 0.f;
        int e = start;
        if ((e & 1) && e < end) {  // align to even edge index
            float2 p0 = pairs[e];
            float2 f0 = __half22float2(Hu[(long)__float_as_int(p0.x) * 64 + lane]);
            ax += f0.x * p0.y; ay += f0.y * p0.y;
            ++e;
        }
        for (; e + 15 < end; e += 16) {
            float4 q[8];
#pragma unroll
            for (int j = 0; j < 8; ++j) q[j] = pp4[(e >> 1) + j];
            __half2 uu[16];
#pragma unroll
            for (int j = 0; j < 8; ++j) {
                uu[2 * j]     = Hu[(long)__float_as_int(q[j].x) * 64 + lane];
                uu[2 * j + 1] = Hu[(long)__float_as_int(q[j].z) * 64 + lane];
            }
#pragma unroll
            for (int j = 0; j < 8; ++j) {
                float2 f0 = __half22float2(uu[2 * j]);
                float2 f1 = __half22float2(uu[2 * j + 1]);
                ax += f0.x * q[j].y + f1.x * q[j].w;
                ay += f0.y * q[j].y + f1.y * q[j].w;
            }
        }
        for (; e + 3 < end; e += 4) {
            float4 q0 = pp4[e >> 1], q1 = pp4[(e >> 1) + 1];
            __half2 u0 = Hu[(long)__float_as_int(q0.x) * 64 + lane];
            __half2 u1 = Hu[(long)__float_as_int(q0.z) * 64 + lane];
            __half2 u2 = Hu[(long)__float_as_int(q1.x) * 64 + lane];
            __half2 u3 = Hu[(long)__float_as_int(q1.z) * 64 + lane];
            float2 f0 = __half22float2(u0), f1 = __half22float2(u1);
            float2 f2 = __half22float2(u2), f3 = __half22float2(u3);
            ax += f0.x * q0.y + f1.x * q0.w + f2.x * q1.y + f3.x * q1.w;
            ay += f0.y * q0.y + f1.y * q0.w + f2.y * q1.y + f3.y * q1.w;
        }
        for (; e < end; ++e) {
            float2 p0 = pairs[e];
            float2 f0 = __half22float2(Hu[(long)__float_as_int(p0.x) * 64 + lane]);
            ax += f0.x * p0.y; ay += f0.y * p0.y;
        }
        float di = dinv[node];
        float d2 = di * di;
        float2 fs = __half22float2(Hu[(long)node * 64 + lane]);
        float2 bz = ((const float2*)bias)[lane];
        float zx = ax + fs.x * d2 + bz.x;
        float zy = ay + fs.y * d2 + bz.y;
        if (RELU) { zx = fmaxf(zx, 0.f); zy = fmaxf(zy, 0.f); }
        if (OUTF16) {
            ((__half2*)outv)[(long)node * 64 + lane] = __float22half2_rn(make_float2(zx, zy));
        } else {
            float2 o = {zx, zy};
            ((float2*)outv)[(long)node * 64 + lane] = o;
        }
    } else {  // F == 64
        const __half* Hh = (const __half*)Hv;
        float acc = 0.f;
        int e = start;
        if ((e & 1) && e < end) {
            float2 p0 = pairs[e];
            acc += __half2float(Hh[(long)__float_as_int(p0.x) * 64 + lane]) * p0.y;
            ++e;
        }
        for (; e + 15 < end; e += 16) {
            float4 q[8];
#pragma unroll
            for (int j = 0; j < 8; ++j) q[j] = pp4[(e >> 1) + j];
            __half uu[16];
#pragma unroll
            for (int j = 0; j < 8; ++j) {
                uu[2 * j]     = Hh[(long)__float_as_int(q[j].x) * 64 + lane];
                uu[2 * j + 1] = Hh[(long)__float_as_int(q[j].z) * 64 + lane];
            }
#pragma unroll
            for (int j = 0; j < 8; ++j)
                acc += __half2float(uu[2 * j]) * q[j].y + __half2float(uu[2 * j + 1]) * q[j].w;
        }
        for (; e + 3 < end; e += 4) {
            float4 q0 = pp4[e >> 1], q1 = pp4[(e >> 1) + 1];
            float h0 = __half2float(Hh[(long)__float_as_int(q0.x) * 64 + lane]);
            float h1 = __half2float(Hh[(long)__float_as_int(q0.z) * 64 + lane]);
            float h2 = __half2float(Hh[(long)__float_as_int(q1.x) * 64 + lane]);
            float h3 = __half2float(Hh[(long)__float_as_int(q1.z) * 64 + lane]);
            acc += h0 * q0.y + h1 * q0.w + h2 * q1.y + h3 * q1.w;
        }
        for (; e < end; ++e) {
            float2 p0 = pairs[e];
            acc += __half2float(Hh[(long)__float_as_int(p0.x) * 64 + lane]) * p0.y;
        }
        float di = dinv[node];
        float z = acc + __half2float(Hh[(long)node * 64 + lane]) * (di * di) + bias[lane];
        if (RELU) z = fmaxf(z, 0.f);
        ((float*)outv)[(long)node * 64 + lane] = z;
    }
}

extern "C" void kernel_launch(void* const* d_in, const int* in_sizes, int n_in,
                              void* d_out, int out_size, void* d_ws, size_t ws_size,
                              hipStream_t stream) {
    const float* x  = (const float*)d_in[0];
    const int*   ei = (const int*)d_in[1];
    const float* W1 = (const float*)d_in[2];
    const float* b1 = (const float*)d_in[3];
    const float* W2 = (const float*)d_in[4];
    const float* b2 = (const float*)d_in[5];
    float* out = (float*)d_out;

    const int N = in_sizes[0] / 128;  // 50000
    const int E = in_sizes[1] / 2;    // 800000
    const int* src = ei;
    const int* dst = ei + E;
    const int NB = (N + 1023) / 1024;  // 49

    // workspace carving (float units; pairs at base => 16B-aligned for float4 loads)
    float* ws = (float*)d_ws;
    float2* pairs = (float2*)ws;                  // [E]
    long off = 2L * E;
    int* posw   = (int*)(ws + off); off += E;
    int* deg    = (int*)(ws + off); off += N;
    int* rowptr = (int*)(ws + off); off += N + 1;
    int* bsum   = (int*)(ws + off); off += 64;
    float* dinv = ws + off;        off += N;
    off = (off + 3) & ~3L;
    f16* Wt1 = (f16*)(ws + off); off += (128 * 136) / 2;
    f16* Wt2 = (f16*)(ws + off); off += (64 * 136) / 2;
    f16* h1  = (f16*)(ws + off); off += (long)N * 64;   // N*128 fp16
    f16* z1  = (f16*)(ws + off); off += (long)N * 64;   // N*128 fp16
    f16* h2  = (f16*)(ws + off); off += (long)N * 32;   // N*64 fp16

    // --- CSR build (atomic pass 1 captures positions) ---
    hipMemsetAsync(deg, 0, (size_t)N * sizeof(int), stream);
    deg_prep_kernel<<<(E + 255) / 256, 256, 0, stream>>>(dst, deg, posw, W1, W2, Wt1, Wt2, E);
    scan1_kernel<<<NB, 1024, 0, stream>>>(deg, rowptr, bsum, dinv, N);
    scan23_kernel<<<NB, 1024, 0, stream>>>(rowptr, bsum, N, NB);

    // --- fused: gemm128 (x@W1 -> h1) + CSR fill ---
    const int GB = (N + 63) / 64;        // 782 gemm blocks
    const int FB = (E + 255) / 256;      // 3125 fill blocks
    fill_gemm_kernel<<<GB + FB, 256, 0, stream>>>(src, dst, posw, dinv, rowptr, pairs, E,
                                                  x, Wt1, h1, N, GB);

    // --- layer 1 aggregate: z1 = f16(relu(agg + self + b1)) ---
    gather_kernel<128, true, true><<<(N + 3) / 4, 256, 0, stream>>>(h1, rowptr, pairs, dinv, b1, z1, N);

    // --- layer 2: h2 = f16(z1@W2); out = agg + self + b2 (fp32) ---
    gemm_kernel<64, false><<<(N + 63) / 64, 256, 0, stream>>>(z1, Wt2, h2, N);
    gather_kernel<64, false, false><<<(N + 3) / 4, 256, 0, stream>>>(h2, rowptr, pairs, dinv, b2, out, N);
}